// Round 6
// baseline (389.725 us; speedup 1.0000x reference)
//
#include <hip/hip_runtime.h>
#include <math.h>

#define TV 6400
#define NTOT 32

typedef __attribute__((ext_vector_type(8))) short short8;
typedef __attribute__((ext_vector_type(4))) short short4v;
typedef __attribute__((ext_vector_type(4))) float f32x4;

__device__ __forceinline__ float b2f(short s) {
  unsigned u = ((unsigned)(unsigned short)s) << 16;
  return __uint_as_float(u);
}
__device__ __forceinline__ short f2b(float f) {
  unsigned u = __float_as_uint(f);
  u = (u + 0x7FFF + ((u >> 16) & 1)) >> 16;
  return (short)u;
}
// fast sigmoid/tanh: v_exp + v_rcp (error ~1e-6, far under bf16 tolerance)
__device__ __forceinline__ float fsig(float x) {
  return __builtin_amdgcn_rcpf(1.f + __expf(-x));
}
__device__ __forceinline__ float ftanh(float x) {
  float x2 = fminf(fmaxf(2.f * x, -80.f), 80.f);
  float t = __expf(x2);
  return (t - 1.f) * __builtin_amdgcn_rcpf(t + 1.f);
}

// ===========================================================================
// Pack weights to bf16 frag-major (unit = 64 lanes x 8 bf16 = one a-frag).
// Units: Wab[0,768) Wu[768,2304) WF[2304,3840) WH[3840,5376) wT[5376,9984).
// Biases fp32 in Pb: bab[0,96) bF[96,288).
// ===========================================================================
__global__ __launch_bounds__(256) void pack_kernel(
    const float* __restrict__ tcn_w, const float* __restrict__ caw,
    const float* __restrict__ cbw, const float* __restrict__ cdw,
    const float* __restrict__ W_ir, const float* __restrict__ W_ii,
    const float* __restrict__ W_in, const float* __restrict__ W_hr,
    const float* __restrict__ W_hi, const float* __restrict__ W_hh,
    const float* __restrict__ cab, const float* __restrict__ cbb,
    const float* __restrict__ b_ir, const float* __restrict__ b_ii,
    const float* __restrict__ b_in,
    short* __restrict__ P, float* __restrict__ Pb)
{
  int idx = blockIdx.x * 256 + threadIdx.x;
  if (idx < 9984) {
    int lane = idx & 63;
    int rest = idx >> 6;
    int c = rest & 1;
    rest >>= 1;
    int mloc = lane & 15, kb = c * 32 + (lane >> 4) * 8;
    short8 v;
    if (rest < 6) {            // Wab
      int m = rest * 16 + mloc;
      for (int i = 0; i < 8; ++i)
        v[i] = f2b(m < 48 ? caw[m * 64 + kb + i] : cbw[(m - 48) * 64 + kb + i]);
    } else if (rest < 18) {    // Wu = cdw [192][64]
      int m = (rest - 6) * 16 + mloc;
      for (int i = 0; i < 8; ++i) v[i] = f2b(cdw[m * 64 + kb + i]);
    } else if (rest < 30) {    // WF
      int m = (rest - 18) * 16 + mloc;
      const float* W = (m < 64) ? W_ir : (m < 128 ? W_ii : W_in);
      int mr = m & 63;
      for (int i = 0; i < 8; ++i) v[i] = f2b(W[mr * 64 + kb + i]);
    } else if (rest < 42) {    // WH
      int m = (rest - 30) * 16 + mloc;
      const float* W = (m < 64) ? W_hr : (m < 128 ? W_hi : W_hh);
      int mr = m & 63;
      for (int i = 0; i < 8; ++i) v[i] = f2b(W[mr * 64 + kb + i]);
    } else {                   // wT: tcn_w [o][c][kk]
      int t = rest - 42;
      int kk = t >> 2, mf = t & 3;
      int o = mf * 16 + mloc;
      for (int i = 0; i < 8; ++i) v[i] = f2b(tcn_w[o * 576 + (kb + i) * 9 + kk]);
    }
    *(short8*)(P + (size_t)idx * 8) = v;
  } else if (idx < 9984 + 288) {
    int r = idx - 9984;
    if (r < 96) Pb[r] = (r < 48) ? cab[r] : cbb[r - 48];
    else {
      int q = r - 96;
      Pb[r] = (q < 64) ? b_ir[q] : (q < 128 ? b_ii[q - 64] : b_in[q - 128]);
    }
  }
}

// ===========================================================================
// fp32 [64][TV] -> KJ8 bf16 [8][TV][8] for hidden and feature
// ===========================================================================
__global__ __launch_bounds__(256) void convert_kernel(
    const float* __restrict__ hid, const float* __restrict__ feat,
    short* __restrict__ hidK, short* __restrict__ featK)
{
  int j = blockIdx.x * 256 + threadIdx.x;
  int gy = blockIdx.y;
  int n = blockIdx.z;
  const float* src = ((gy < 8) ? hid : feat) + ((long)n * 64 + (long)(gy & 7) * 8) * TV + j;
  short* dst = ((gy < 8) ? hidK : featK) + (((long)n * 8 + (gy & 7)) * TV + j) * 8;
  short8 o;
#pragma unroll
  for (int i = 0; i < 8; ++i) o[i] = f2b(src[(long)i * TV]);
  *(short8*)dst = o;
}

// ===========================================================================
// ab = (caw|cbw) @ hid, M=96 in ONE m-pass -> abK (KJ8)
// ===========================================================================
__global__ __launch_bounds__(256) void ab_gemm(
    const short8* __restrict__ Wp, const short8* __restrict__ Bk,
    short* __restrict__ Cout, const float* __restrict__ bias)
{
  const int tid = threadIdx.x;
  const int lane = tid & 63, w = tid >> 6;
  const int q = lane >> 4, lj = lane & 15;
  const int j0 = blockIdx.x * 128;
  const int n = blockIdx.y;
  const short8* Bn = Bk + (long)n * 8 * TV;
  short* Cn = Cout + (long)n * 96 * TV;

  f32x4 acc[6][2];
  for (int a = 0; a < 6; ++a) for (int b = 0; b < 2; ++b)
    acc[a][b] = (f32x4){0.f, 0.f, 0.f, 0.f};

  for (int c = 0; c < 2; ++c) {
    short8 bf0 = Bn[(long)(c * 4 + q) * TV + j0 + (w * 2 + 0) * 16 + lj];
    short8 bf1 = Bn[(long)(c * 4 + q) * TV + j0 + (w * 2 + 1) * 16 + lj];
#pragma unroll
    for (int mf = 0; mf < 6; ++mf) {
      short8 af = Wp[(mf * 2 + c) * 64 + lane];
      acc[mf][0] = __builtin_amdgcn_mfma_f32_16x16x32_bf16(af, bf0, acc[mf][0], 0, 0, 0);
      acc[mf][1] = __builtin_amdgcn_mfma_f32_16x16x32_bf16(af, bf1, acc[mf][1], 0, 0, 0);
    }
  }
#pragma unroll
  for (int mf = 0; mf < 6; ++mf) {
    int k0 = mf * 16 + q * 4;
    int g = k0 >> 3, i0 = k0 & 7;
    float bv[4];
#pragma unroll
    for (int r = 0; r < 4; ++r) bv[r] = bias[k0 + r];
#pragma unroll
    for (int jf = 0; jf < 2; ++jf) {
      int j = j0 + (w * 2 + jf) * 16 + lj;
      short4v o4;
#pragma unroll
      for (int r = 0; r < 4; ++r) o4[r] = f2b(acc[mf][jf][r] + bv[r]);
      *(short4v*)(Cn + ((long)g * TV + j) * 8 + i0) = o4;
    }
  }
}

// ===========================================================================
// Attention split-K partial from abK (KJ8 bf16)
// ===========================================================================
__global__ __launch_bounds__(256) void att_partial(
    const short* __restrict__ abK, float* __restrict__ partial)
{
  const int ch = blockIdx.x, i = blockIdx.y, n = blockIdx.z;
  __shared__ float sA[6400], sB[6400];
  const int tid = threadIdx.x;
  const long nb = (long)n * 96 * TV;
  const int t0 = ch * 16;
  for (int idx = tid; idx < 800; idx += 256) {
    int gh = idx / 400, jl = idx - gh * 400;
    long j = (long)t0 * 25 + jl;
    short8 va = *(const short8*)&abK[nb + ((long)(2 * i + gh) * TV + j) * 8];
    short8 vb = *(const short8*)&abK[nb + ((long)(6 + 2 * i + gh) * TV + j) * 8];
#pragma unroll
    for (int e = 0; e < 8; ++e) {
      sA[(gh * 8 + e) * 400 + jl] = b2f(va[e]);
      sB[(gh * 8 + e) * 400 + jl] = b2f(vb[e]);
    }
  }
  __syncthreads();
  const int a0 = tid >> 4, b0 = tid & 15;
  const int v1 = a0 + 16, w1 = b0 + 16;
  const int v1c = (v1 < 25) ? v1 : 0, w1c = (w1 < 25) ? w1 : 0;
  float acc00 = 0, acc01 = 0, acc10 = 0, acc11 = 0;
#pragma unroll 8
  for (int r = 0; r < 256; ++r) {
    float av0 = sA[r * 25 + a0], av1 = sA[r * 25 + v1c];
    float bw0 = sB[r * 25 + b0], bw1 = sB[r * 25 + w1c];
    acc00 += av0 * bw0; acc01 += av0 * bw1;
    acc10 += av1 * bw0; acc11 += av1 * bw1;
  }
  const float scale = 1.0f / 4096.0f;
  float* pp = partial + (((long)(n * 3 + i) * 16) + ch) * 625;
  pp[a0 * 25 + b0] = acc00 * scale;
  if (w1 < 25) pp[a0 * 25 + w1] = acc01 * scale;
  if (v1 < 25) pp[v1 * 25 + b0] = acc10 * scale;
  if (v1 < 25 && w1 < 25) pp[v1 * 25 + w1] = acc11 * scale;
}

// ===========================================================================
// Reduce partials, column softmax, +A+PA -> attP in bf16 A-frag layout
// ===========================================================================
__global__ __launch_bounds__(256) void att_reduce(
    const float* __restrict__ partial, const float* __restrict__ Amat,
    const float* __restrict__ PAmat, short* __restrict__ attP)
{
  const int i = blockIdx.x, n = blockIdx.y;
  __shared__ float sL[625];
  const int tid = threadIdx.x;
  const float* pp = partial + ((long)(n * 3 + i) * 16) * 625;
  for (int idx = tid; idx < 625; idx += 256) {
    float s = 0.f;
#pragma unroll
    for (int c = 0; c < 16; ++c) s += pp[c * 625 + idx];
    sL[idx] = s;
  }
  __syncthreads();
  if (tid < 25) {
    const int w = tid;
    float mx = -1e30f;
#pragma unroll
    for (int v = 0; v < 25; ++v) mx = fmaxf(mx, sL[v * 25 + w]);
    float e[25];
    float s = 0.f;
#pragma unroll
    for (int v = 0; v < 25; ++v) { e[v] = __expf(sL[v * 25 + w] - mx); s += e[v]; }
    float inv = 1.f / s;
#pragma unroll
    for (int v = 0; v < 25; ++v)
      sL[v * 25 + w] = e[v] * inv + Amat[i * 625 + v * 25 + w] + PAmat[i * 625 + v * 25 + w];
  }
  __syncthreads();
  if (tid < 128) {
    int wf = tid >> 6, lane = tid & 63;
    int q = lane >> 4, lj = lane & 15;
    int w = wf * 16 + lj;
    short8 o = {0, 0, 0, 0, 0, 0, 0, 0};
    if (w < 25) {
#pragma unroll
      for (int e2 = 0; e2 < 8; ++e2) {
        int v = q * 8 + e2;
        if (v < 25) o[e2] = f2b(sL[v * 25 + w]);
      }
    }
    *(short8*)(attP + (size_t)(((long)(n * 3 + i) * 2 + wf) * 64 + lane) * 8) = o;
  }
}

// ===========================================================================
// FUSED GCN: u = cdw@hid (MFMA) -> LDS [o][t][v] (stride 136, b128-aligned);
// y = sum_i u_i x att_i (MFMA, B-frag = one ds_read_b128); gBN+residual+relu.
// Pad slots v=25..31 of each 32-group are ZEROED: leftover LDS bits can be
// Inf/NaN as bf16, and 0*Inf = NaN -> fmaxf(NaN,0)=0 silently corrupts
// (round-5 failure). Explicit zero-fill removes the hazard.
// ===========================================================================
#define UST 136  // u-tile LDS row stride (shorts)
#define OST 101
__global__ __launch_bounds__(256) void gcn_fused(
    const short8* __restrict__ Wu, const short8* __restrict__ attP,
    const short8* __restrict__ hidK, const float* __restrict__ cdb,
    const float* __restrict__ gg, const float* __restrict__ gb,
    const float* __restrict__ gm, const float* __restrict__ gv,
    short* __restrict__ gcnK)
{
  __shared__ __align__(16) short uT[192 * UST];
  __shared__ short sOut[64 * OST];
  __shared__ float A2[64], B2[64];
  const int tid = threadIdx.x;
  if (tid < 64) {
    float sc = gg[tid] * rsqrtf(gv[tid] + 1e-5f);
    A2[tid] = sc;
    float bias = cdb[tid] + cdb[64 + tid] + cdb[128 + tid];
    B2[tid] = bias * sc + (gb[tid] - gm[tid] * sc);
  }
  // zero-fill pad slots 25..31 of each 32-group (192 rows x 4 groups x 7)
  for (int idx = tid; idx < 5376; idx += 256) {
    int row = idx / 28, rr = idx - row * 28;
    int g = rr / 7, s = 25 + (rr - g * 7);
    uT[row * UST + g * 32 + s] = 0;
  }
  const int lane = tid & 63, w = tid >> 6;
  const int q = lane >> 4, lj = lane & 15;
  const int tt = blockIdx.x, n = blockIdx.y;
  const int jb = tt * 100;
  const short8* Hn = hidK + (long)n * 8 * TV;

  // ---- phase 1: u-tile [192][100] via MFMA; wave w does mf = 3w..3w+2
  f32x4 uacc[3][7];
  for (int a = 0; a < 3; ++a) for (int b = 0; b < 7; ++b)
    uacc[a][b] = (f32x4){0.f, 0.f, 0.f, 0.f};
  for (int c = 0; c < 2; ++c) {
    short8 bf[7];
#pragma unroll
    for (int jf = 0; jf < 7; ++jf)
      bf[jf] = Hn[(long)(c * 4 + q) * TV + jb + jf * 16 + lj];
#pragma unroll
    for (int ml = 0; ml < 3; ++ml) {
      short8 af = Wu[((w * 3 + ml) * 2 + c) * 64 + lane];
#pragma unroll
      for (int jf = 0; jf < 7; ++jf)
        uacc[ml][jf] = __builtin_amdgcn_mfma_f32_16x16x32_bf16(af, bf[jf], uacc[ml][jf], 0, 0, 0);
    }
  }
#pragma unroll
  for (int ml = 0; ml < 3; ++ml) {
    int row0 = (w * 3 + ml) * 16 + q * 4;
#pragma unroll
    for (int jf = 0; jf < 7; ++jf) {
      int col = jf * 16 + lj;
      if (col < 100) {
        int cc = (col / 25) * 32 + (col % 25);   // [t][v] within row
#pragma unroll
        for (int r = 0; r < 4; ++r)
          uT[(row0 + r) * UST + cc] = f2b(uacc[ml][jf][r]);
      }
    }
  }
  __syncthreads();

  // ---- phase 2: mixing for t_local = w; B-frag = aligned ds_read_b128
  const int colt = w * 25;
  short8 attA[6];
#pragma unroll
  for (int i = 0; i < 3; ++i)
#pragma unroll
    for (int wf = 0; wf < 2; ++wf)
      attA[i * 2 + wf] = attP[((long)(n * 3 + i) * 2 + wf) * 64 + lane];

  f32x4 macc[2][4];
  for (int a = 0; a < 2; ++a) for (int b = 0; b < 4; ++b)
    macc[a][b] = (f32x4){0.f, 0.f, 0.f, 0.f};
#pragma unroll
  for (int i = 0; i < 3; ++i) {
#pragma unroll
    for (int of = 0; of < 4; ++of) {
      int row = i * 64 + of * 16 + lj;
      short8 bf = *(const short8*)&uT[row * UST + w * 32 + q * 8];
      macc[0][of] = __builtin_amdgcn_mfma_f32_16x16x32_bf16(attA[i * 2 + 0], bf, macc[0][of], 0, 0, 0);
      macc[1][of] = __builtin_amdgcn_mfma_f32_16x16x32_bf16(attA[i * 2 + 1], bf, macc[1][of], 0, 0, 0);
    }
  }
#pragma unroll
  for (int wf = 0; wf < 2; ++wf)
#pragma unroll
    for (int of = 0; of < 4; ++of)
#pragma unroll
      for (int r = 0; r < 4; ++r) {
        int wl = wf * 16 + q * 4 + r;
        if (wl < 25)
          sOut[(of * 16 + lj) * OST + colt + wl] = f2b(macc[wf][of][r]);
      }
  __syncthreads();

  // ---- epilogue: coalesced KJ8 in/out
  const short* HnS = (const short*)Hn;
  short* Gn = gcnK + (long)n * 64 * TV;
  for (int u2 = tid; u2 < 800; u2 += 256) {
    int col = u2 % 100, og = u2 / 100;
    long ubase = ((long)og * TV + jb + col) * 8;
    short8 h8 = *(const short8*)&HnS[ubase];
    short8 o8;
#pragma unroll
    for (int e = 0; e < 8; ++e) {
      int o = og * 8 + e;
      float acc = b2f(sOut[o * OST + col]);
      float vv = fmaxf(acc * A2[o] + B2[o] + b2f(h8[e]), 0.f);
      o8[e] = f2b(vv);
    }
    *(short8*)&Gn[ubase] = o8;
  }
}

// ===========================================================================
// FUSED TCN+GRU (j-block 64): tcn MFMA -> tBN+residual+relu -> msg in LDS;
// H = WH@msg (LDS b128 frags), F = WF@featK; fast gates; out fp32.
// Explicit barrier after staging: A2/B2/sW must be visible to all waves
// before any epilogue read (round-5 latent race).
// ===========================================================================
__global__ __launch_bounds__(256) void tcn_gru_fused(
    const short8* __restrict__ wTp, const short8* __restrict__ gcnK,
    const short* __restrict__ hidK, const float* __restrict__ tcn_b,
    const float* __restrict__ tg, const float* __restrict__ tb2,
    const float* __restrict__ tm, const float* __restrict__ tvv,
    const short8* __restrict__ WFp, const short8* __restrict__ WHp,
    const float* __restrict__ bF, const short8* __restrict__ featK,
    float* __restrict__ outp)
{
  __shared__ __align__(16) char smem[49152];   // sW; later sOut (fp32 64x68)
  __shared__ __align__(16) short sMsg[4096];   // msg KJ8 [8][64][8]
  __shared__ float sBias[192];
  __shared__ float A2[64], B2[64];
  short8* sW = (short8*)smem;
  float* sOut = (float*)smem;
  const int tid = threadIdx.x;
  for (int idx = tid; idx < 1536; idx += 256) {
    sW[idx] = WFp[idx];
    sW[1536 + idx] = WHp[idx];
  }
  if (tid < 192) sBias[tid] = bF[tid];
  if (tid < 64) {
    float sc = tg[tid] * rsqrtf(tvv[tid] + 1e-5f);
    A2[tid] = sc;
    B2[tid] = tcn_b[tid] * sc + (tb2[tid] - tm[tid] * sc);
  }
  __syncthreads();   // A2/B2 (+sW) visible to all waves before use

  const int lane = tid & 63, w = tid >> 6;
  const int q = lane >> 4, lj = lane & 15;
  const int j0 = blockIdx.x * 64, n = blockIdx.y;
  const int jcol = j0 + w * 16 + lj;
  const int cloc = w * 16 + lj;
  const short8* Bn = gcnK + (long)n * 8 * TV;
  const short8 zero8 = {0, 0, 0, 0, 0, 0, 0, 0};

  // ---- tcn GEMM (9 shifted K=64 accumulations)
  f32x4 acc[4];
  for (int a = 0; a < 4; ++a) acc[a] = (f32x4){0.f, 0.f, 0.f, 0.f};
  for (int kk = 0; kk < 9; ++kk) {
    const int shift = (kk - 4) * 25;
    for (int c = 0; c < 2; ++c) {
      int col = jcol + shift;
      bool valid = ((unsigned)col < (unsigned)TV);
      short8 t = Bn[(long)(c * 4 + q) * TV + (valid ? col : 0)];
      short8 bf = valid ? t : zero8;
#pragma unroll
      for (int mf = 0; mf < 4; ++mf) {
        short8 af = wTp[((kk * 4 + mf) * 2 + c) * 64 + lane];
        acc[mf] = __builtin_amdgcn_mfma_f32_16x16x32_bf16(af, bf, acc[mf], 0, 0, 0);
      }
    }
  }
  // ---- tcn epilogue -> sMsg (KJ8)
  const short* HnS = hidK + (long)n * 64 * TV;
#pragma unroll
  for (int mf = 0; mf < 4; ++mf) {
    int k0 = mf * 16 + q * 4;
    int g = k0 >> 3, i0 = k0 & 7;
    short4v h4 = *(const short4v*)&HnS[((long)g * TV + jcol) * 8 + i0];
    short4v o4;
#pragma unroll
    for (int r = 0; r < 4; ++r) {
      float v = acc[mf][r] * A2[k0 + r] + B2[k0 + r] + b2f(h4[r]);
      o4[r] = f2b(fmaxf(v, 0.f));
    }
    *(short4v*)&sMsg[(g * 64 + cloc) * 8 + i0] = o4;
  }
  __syncthreads();   // sMsg complete

  // ---- GRU GEMMs
  f32x4 accF[12], accH[12];
  for (int a = 0; a < 12; ++a) {
    accF[a] = (f32x4){0.f, 0.f, 0.f, 0.f};
    accH[a] = (f32x4){0.f, 0.f, 0.f, 0.f};
  }
  const short8* Fn = featK + (long)n * 8 * TV;
  for (int c = 0; c < 2; ++c) {
    short8 bFf = Fn[(long)(c * 4 + q) * TV + jcol];
    short8 bHf = *(const short8*)&sMsg[((c * 4 + q) * 64 + cloc) * 8];
#pragma unroll
    for (int mf = 0; mf < 12; ++mf) {
      short8 af = sW[(mf * 2 + c) * 64 + lane];
      accF[mf] = __builtin_amdgcn_mfma_f32_16x16x32_bf16(af, bFf, accF[mf], 0, 0, 0);
      short8 ah = sW[1536 + (mf * 2 + c) * 64 + lane];
      accH[mf] = __builtin_amdgcn_mfma_f32_16x16x32_bf16(ah, bHf, accH[mf], 0, 0, 0);
    }
  }
  __syncthreads();   // weights dead; sOut aliases sW

  // ---- gates (fast transcendentals)
#pragma unroll
  for (int mf = 0; mf < 4; ++mf) {
    int k0 = mf * 16 + q * 4;
    int g = k0 >> 3, i0 = k0 & 7;
    short4v h4 = *(const short4v*)&HnS[((long)g * TV + jcol) * 8 + i0];
#pragma unroll
    for (int r = 0; r < 4; ++r) {
      int o = k0 + r;
      float rp = accF[mf][r] + sBias[o] + accH[mf][r];
      float zp = accF[mf + 4][r] + sBias[64 + o] + accH[mf + 4][r];
      float np = accF[mf + 8][r] + sBias[128 + o];
      float rv = fsig(rp);
      float zv = fsig(zp);
      float nn = ftanh(np + rv * accH[mf + 8][r]);
      float hv = b2f(h4[r]);
      sOut[o * 68 + cloc] = (1.f - zv) * nn + zv * hv;
    }
  }
  __syncthreads();
  float* On = outp + (long)n * 64 * TV;
  for (int u2 = tid; u2 < 1024; u2 += 256) {
    int row = u2 >> 4, c4 = u2 & 15;
    float4 vv = *(const float4*)&sOut[row * 68 + c4 * 4];
    *(float4*)&On[(long)row * TV + j0 + c4 * 4] = vv;
  }
}

// ===========================================================================
extern "C" void kernel_launch(void* const* d_in, const int* in_sizes, int n_in,
                              void* d_out, int out_size, void* d_ws, size_t ws_size,
                              hipStream_t stream)
{
  const float* feature = (const float*)d_in[0];
  const float* hidden  = (const float*)d_in[1];
  const float* Amat    = (const float*)d_in[2];
  const float* PAmat   = (const float*)d_in[3];
  const float* caw = (const float*)d_in[4];
  const float* cab = (const float*)d_in[5];
  const float* cbw = (const float*)d_in[6];
  const float* cbb = (const float*)d_in[7];
  const float* cdw = (const float*)d_in[8];
  const float* cdb = (const float*)d_in[9];
  const float* gbn_g = (const float*)d_in[10];
  const float* gbn_b = (const float*)d_in[11];
  const float* gbn_m = (const float*)d_in[12];
  const float* gbn_v = (const float*)d_in[13];
  const float* tcn_w = (const float*)d_in[14];
  const float* tcn_b = (const float*)d_in[15];
  const float* tbn_g = (const float*)d_in[16];
  const float* tbn_b = (const float*)d_in[17];
  const float* tbn_m = (const float*)d_in[18];
  const float* tbn_v = (const float*)d_in[19];
  const float* W_ir = (const float*)d_in[20];
  const float* W_ii = (const float*)d_in[21];
  const float* W_in = (const float*)d_in[22];
  const float* W_hr = (const float*)d_in[23];
  const float* W_hi = (const float*)d_in[24];
  const float* W_hh = (const float*)d_in[25];
  const float* b_ir = (const float*)d_in[26];
  const float* b_ii = (const float*)d_in[27];
  const float* b_in = (const float*)d_in[28];
  float* out = (float*)d_out;

  // n-chunk sizing (layout depends only on ws_size)
  int Nc = NTOT;
  while (Nc > 1) {
    size_t need = (size_t)288 * TV * 2 * Nc + (size_t)Nc * 30000 * 4 +
                  (size_t)Nc * 3072 * 2 + 79872 * 2 + 288 * 4 + 4096;
    if (need <= ws_size) break;
    Nc >>= 1;
  }

  char* p = (char*)d_ws;
  short* hidK = (short*)p;  p += (size_t)Nc * 64 * TV * 2;
  short* featK = (short*)p; p += (size_t)Nc * 64 * TV * 2;
  short* abK = (short*)p;   p += (size_t)Nc * 96 * TV * 2;
  short* gcnK = (short*)p;  p += (size_t)Nc * 64 * TV * 2;
  float* partial = (float*)p; p += (size_t)Nc * 30000 * 4;
  short* attP = (short*)p;    p += (size_t)Nc * 3072 * 2;
  p = (char*)(((size_t)p + 15) & ~(size_t)15);
  short* P = (short*)p;       p += 79872 * 2;
  float* Pb = (float*)p;

  pack_kernel<<<dim3(41), dim3(256), 0, stream>>>(
      tcn_w, caw, cbw, cdw, W_ir, W_ii, W_in, W_hr, W_hi, W_hh,
      cab, cbb, b_ir, b_ii, b_in, P, Pb);

  const long s64 = (long)64 * TV;
  for (int c0 = 0; c0 < NTOT; c0 += Nc) {
    const float* hidc = hidden + (long)c0 * s64;
    const float* featc = feature + (long)c0 * s64;
    float* outc = out + (long)c0 * s64;

    convert_kernel<<<dim3(25, 16, Nc), 256, 0, stream>>>(hidc, featc, hidK, featK);
    ab_gemm<<<dim3(50, Nc), 256, 0, stream>>>(
        (const short8*)P, (const short8*)hidK, abK, Pb);
    att_partial<<<dim3(16, 3, Nc), 256, 0, stream>>>(abK, partial);
    att_reduce<<<dim3(3, Nc), 256, 0, stream>>>(partial, Amat, PAmat, attP);
    gcn_fused<<<dim3(64, Nc), 256, 0, stream>>>(
        (const short8*)P + 768, (const short8*)attP, (const short8*)hidK,
        cdb, gbn_g, gbn_b, gbn_m, gbn_v, gcnK);
    tcn_gru_fused<<<dim3(100, Nc), 256, 0, stream>>>(
        (const short8*)P + 5376, (const short8*)gcnK, hidK, tcn_b,
        tbn_g, tbn_b, tbn_m, tbn_v,
        (const short8*)P + 2304, (const short8*)P + 3840, Pb + 96,
        (const short8*)featK, outc);
  }
}

// Round 7
// 366.967 us; speedup vs baseline: 1.0620x; 1.0620x over previous
//
#include <hip/hip_runtime.h>
#include <math.h>

#define TV 6400
#define NTOT 32

typedef __attribute__((ext_vector_type(8))) short short8;
typedef __attribute__((ext_vector_type(4))) short short4v;
typedef __attribute__((ext_vector_type(4))) float f32x4;

__device__ __forceinline__ float b2f(short s) {
  unsigned u = ((unsigned)(unsigned short)s) << 16;
  return __uint_as_float(u);
}
__device__ __forceinline__ short f2b(float f) {
  unsigned u = __float_as_uint(f);
  u = (u + 0x7FFF + ((u >> 16) & 1)) >> 16;
  return (short)u;
}
// fast sigmoid/tanh: v_exp + v_rcp (error ~1e-6, far under bf16 tolerance)
__device__ __forceinline__ float fsig(float x) {
  return __builtin_amdgcn_rcpf(1.f + __expf(-x));
}
__device__ __forceinline__ float ftanh(float x) {
  float x2 = fminf(fmaxf(2.f * x, -80.f), 80.f);
  float t = __expf(x2);
  return (t - 1.f) * __builtin_amdgcn_rcpf(t + 1.f);
}

// ===========================================================================
// Pack weights to bf16 frag-major (unit = 64 lanes x 8 bf16 = one a-frag).
// Units: Wab[0,768) Wu[768,2304) WF[2304,3840) WH[3840,5376) wT[5376,9984).
// Biases fp32 in Pb: bab[0,96) bF[96,288).
// ===========================================================================
__global__ __launch_bounds__(256) void pack_kernel(
    const float* __restrict__ tcn_w, const float* __restrict__ caw,
    const float* __restrict__ cbw, const float* __restrict__ cdw,
    const float* __restrict__ W_ir, const float* __restrict__ W_ii,
    const float* __restrict__ W_in, const float* __restrict__ W_hr,
    const float* __restrict__ W_hi, const float* __restrict__ W_hh,
    const float* __restrict__ cab, const float* __restrict__ cbb,
    const float* __restrict__ b_ir, const float* __restrict__ b_ii,
    const float* __restrict__ b_in,
    short* __restrict__ P, float* __restrict__ Pb)
{
  int idx = blockIdx.x * 256 + threadIdx.x;
  if (idx < 9984) {
    int lane = idx & 63;
    int rest = idx >> 6;
    int c = rest & 1;
    rest >>= 1;
    int mloc = lane & 15, kb = c * 32 + (lane >> 4) * 8;
    short8 v;
    if (rest < 6) {            // Wab
      int m = rest * 16 + mloc;
      for (int i = 0; i < 8; ++i)
        v[i] = f2b(m < 48 ? caw[m * 64 + kb + i] : cbw[(m - 48) * 64 + kb + i]);
    } else if (rest < 18) {    // Wu = cdw [192][64]
      int m = (rest - 6) * 16 + mloc;
      for (int i = 0; i < 8; ++i) v[i] = f2b(cdw[m * 64 + kb + i]);
    } else if (rest < 30) {    // WF
      int m = (rest - 18) * 16 + mloc;
      const float* W = (m < 64) ? W_ir : (m < 128 ? W_ii : W_in);
      int mr = m & 63;
      for (int i = 0; i < 8; ++i) v[i] = f2b(W[mr * 64 + kb + i]);
    } else if (rest < 42) {    // WH
      int m = (rest - 30) * 16 + mloc;
      const float* W = (m < 64) ? W_hr : (m < 128 ? W_hi : W_hh);
      int mr = m & 63;
      for (int i = 0; i < 8; ++i) v[i] = f2b(W[mr * 64 + kb + i]);
    } else {                   // wT: tcn_w [o][c][kk]
      int t = rest - 42;
      int kk = t >> 2, mf = t & 3;
      int o = mf * 16 + mloc;
      for (int i = 0; i < 8; ++i) v[i] = f2b(tcn_w[o * 576 + (kb + i) * 9 + kk]);
    }
    *(short8*)(P + (size_t)idx * 8) = v;
  } else if (idx < 9984 + 288) {
    int r = idx - 9984;
    if (r < 96) Pb[r] = (r < 48) ? cab[r] : cbb[r - 48];
    else {
      int q = r - 96;
      Pb[r] = (q < 64) ? b_ir[q] : (q < 128 ? b_ii[q - 64] : b_in[q - 128]);
    }
  }
}

// ===========================================================================
// fp32 [64][TV] -> KJ8 bf16 [8][TV][8] for hidden and feature
// ===========================================================================
__global__ __launch_bounds__(256) void convert_kernel(
    const float* __restrict__ hid, const float* __restrict__ feat,
    short* __restrict__ hidK, short* __restrict__ featK)
{
  int j = blockIdx.x * 256 + threadIdx.x;
  int gy = blockIdx.y;
  int n = blockIdx.z;
  const float* src = ((gy < 8) ? hid : feat) + ((long)n * 64 + (long)(gy & 7) * 8) * TV + j;
  short* dst = ((gy < 8) ? hidK : featK) + (((long)n * 8 + (gy & 7)) * TV + j) * 8;
  short8 o;
#pragma unroll
  for (int i = 0; i < 8; ++i) o[i] = f2b(src[(long)i * TV]);
  *(short8*)dst = o;
}

// ===========================================================================
// ab = (caw|cbw) @ hid, M=96 in ONE m-pass -> abK (KJ8)
// ===========================================================================
__global__ __launch_bounds__(256) void ab_gemm(
    const short8* __restrict__ Wp, const short8* __restrict__ Bk,
    short* __restrict__ Cout, const float* __restrict__ bias)
{
  const int tid = threadIdx.x;
  const int lane = tid & 63, w = tid >> 6;
  const int q = lane >> 4, lj = lane & 15;
  const int j0 = blockIdx.x * 128;
  const int n = blockIdx.y;
  const short8* Bn = Bk + (long)n * 8 * TV;
  short* Cn = Cout + (long)n * 96 * TV;

  f32x4 acc[6][2];
  for (int a = 0; a < 6; ++a) for (int b = 0; b < 2; ++b)
    acc[a][b] = (f32x4){0.f, 0.f, 0.f, 0.f};

  for (int c = 0; c < 2; ++c) {
    short8 bf0 = Bn[(long)(c * 4 + q) * TV + j0 + (w * 2 + 0) * 16 + lj];
    short8 bf1 = Bn[(long)(c * 4 + q) * TV + j0 + (w * 2 + 1) * 16 + lj];
#pragma unroll
    for (int mf = 0; mf < 6; ++mf) {
      short8 af = Wp[(mf * 2 + c) * 64 + lane];
      acc[mf][0] = __builtin_amdgcn_mfma_f32_16x16x32_bf16(af, bf0, acc[mf][0], 0, 0, 0);
      acc[mf][1] = __builtin_amdgcn_mfma_f32_16x16x32_bf16(af, bf1, acc[mf][1], 0, 0, 0);
    }
  }
#pragma unroll
  for (int mf = 0; mf < 6; ++mf) {
    int k0 = mf * 16 + q * 4;
    int g = k0 >> 3, i0 = k0 & 7;
    float bv[4];
#pragma unroll
    for (int r = 0; r < 4; ++r) bv[r] = bias[k0 + r];
#pragma unroll
    for (int jf = 0; jf < 2; ++jf) {
      int j = j0 + (w * 2 + jf) * 16 + lj;
      short4v o4;
#pragma unroll
      for (int r = 0; r < 4; ++r) o4[r] = f2b(acc[mf][jf][r] + bv[r]);
      *(short4v*)(Cn + ((long)g * TV + j) * 8 + i0) = o4;
    }
  }
}

// ===========================================================================
// Attention split-K partial from abK (KJ8 bf16)
// ===========================================================================
__global__ __launch_bounds__(256) void att_partial(
    const short* __restrict__ abK, float* __restrict__ partial)
{
  const int ch = blockIdx.x, i = blockIdx.y, n = blockIdx.z;
  __shared__ float sA[6400], sB[6400];
  const int tid = threadIdx.x;
  const long nb = (long)n * 96 * TV;
  const int t0 = ch * 16;
  for (int idx = tid; idx < 800; idx += 256) {
    int gh = idx / 400, jl = idx - gh * 400;
    long j = (long)t0 * 25 + jl;
    short8 va = *(const short8*)&abK[nb + ((long)(2 * i + gh) * TV + j) * 8];
    short8 vb = *(const short8*)&abK[nb + ((long)(6 + 2 * i + gh) * TV + j) * 8];
#pragma unroll
    for (int e = 0; e < 8; ++e) {
      sA[(gh * 8 + e) * 400 + jl] = b2f(va[e]);
      sB[(gh * 8 + e) * 400 + jl] = b2f(vb[e]);
    }
  }
  __syncthreads();
  const int a0 = tid >> 4, b0 = tid & 15;
  const int v1 = a0 + 16, w1 = b0 + 16;
  const int v1c = (v1 < 25) ? v1 : 0, w1c = (w1 < 25) ? w1 : 0;
  float acc00 = 0, acc01 = 0, acc10 = 0, acc11 = 0;
#pragma unroll 8
  for (int r = 0; r < 256; ++r) {
    float av0 = sA[r * 25 + a0], av1 = sA[r * 25 + v1c];
    float bw0 = sB[r * 25 + b0], bw1 = sB[r * 25 + w1c];
    acc00 += av0 * bw0; acc01 += av0 * bw1;
    acc10 += av1 * bw0; acc11 += av1 * bw1;
  }
  const float scale = 1.0f / 4096.0f;
  float* pp = partial + (((long)(n * 3 + i) * 16) + ch) * 625;
  pp[a0 * 25 + b0] = acc00 * scale;
  if (w1 < 25) pp[a0 * 25 + w1] = acc01 * scale;
  if (v1 < 25) pp[v1 * 25 + b0] = acc10 * scale;
  if (v1 < 25 && w1 < 25) pp[v1 * 25 + w1] = acc11 * scale;
}

// ===========================================================================
// Reduce partials, column softmax, +A+PA -> attP in bf16 A-frag layout
// ===========================================================================
__global__ __launch_bounds__(256) void att_reduce(
    const float* __restrict__ partial, const float* __restrict__ Amat,
    const float* __restrict__ PAmat, short* __restrict__ attP)
{
  const int i = blockIdx.x, n = blockIdx.y;
  __shared__ float sL[625];
  const int tid = threadIdx.x;
  const float* pp = partial + ((long)(n * 3 + i) * 16) * 625;
  for (int idx = tid; idx < 625; idx += 256) {
    float s = 0.f;
#pragma unroll
    for (int c = 0; c < 16; ++c) s += pp[c * 625 + idx];
    sL[idx] = s;
  }
  __syncthreads();
  if (tid < 25) {
    const int w = tid;
    float mx = -1e30f;
#pragma unroll
    for (int v = 0; v < 25; ++v) mx = fmaxf(mx, sL[v * 25 + w]);
    float e[25];
    float s = 0.f;
#pragma unroll
    for (int v = 0; v < 25; ++v) { e[v] = __expf(sL[v * 25 + w] - mx); s += e[v]; }
    float inv = 1.f / s;
#pragma unroll
    for (int v = 0; v < 25; ++v)
      sL[v * 25 + w] = e[v] * inv + Amat[i * 625 + v * 25 + w] + PAmat[i * 625 + v * 25 + w];
  }
  __syncthreads();
  if (tid < 128) {
    int wf = tid >> 6, lane = tid & 63;
    int q = lane >> 4, lj = lane & 15;
    int w = wf * 16 + lj;
    short8 o = {0, 0, 0, 0, 0, 0, 0, 0};
    if (w < 25) {
#pragma unroll
      for (int e2 = 0; e2 < 8; ++e2) {
        int v = q * 8 + e2;
        if (v < 25) o[e2] = f2b(sL[v * 25 + w]);
      }
    }
    *(short8*)(attP + (size_t)(((long)(n * 3 + i) * 2 + wf) * 64 + lane) * 8) = o;
  }
}

// ===========================================================================
// FUSED GCN: u = cdw@hid (MFMA) -> LDS [o][t][v]; mixing MFMA; gBN+res+relu.
// sOut ALIASES uT (dead after phase-2 MFMA reads; extra barrier guards it)
// -> LDS ~52.8 KB -> 3 blocks/CU. Pad slots zeroed (NaN hazard, round 5).
// ===========================================================================
#define UST 136
#define OST 101
__global__ __launch_bounds__(256) void gcn_fused(
    const short8* __restrict__ Wu, const short8* __restrict__ attP,
    const short8* __restrict__ hidK, const float* __restrict__ cdb,
    const float* __restrict__ gg, const float* __restrict__ gb,
    const float* __restrict__ gm, const float* __restrict__ gv,
    short* __restrict__ gcnK)
{
  __shared__ __align__(16) short uT[192 * UST];
  __shared__ float A2[64], B2[64];
  short* sOut = uT;   // aliased: used only after phase-2 reads complete
  const int tid = threadIdx.x;
  if (tid < 64) {
    float sc = gg[tid] * rsqrtf(gv[tid] + 1e-5f);
    A2[tid] = sc;
    float bias = cdb[tid] + cdb[64 + tid] + cdb[128 + tid];
    B2[tid] = bias * sc + (gb[tid] - gm[tid] * sc);
  }
  // zero-fill pad slots 25..31 of each 32-group
  for (int idx = tid; idx < 5376; idx += 256) {
    int row = idx / 28, rr = idx - row * 28;
    int g = rr / 7, s = 25 + (rr - g * 7);
    uT[row * UST + g * 32 + s] = 0;
  }
  const int lane = tid & 63, w = tid >> 6;
  const int q = lane >> 4, lj = lane & 15;
  const int tt = blockIdx.x, n = blockIdx.y;
  const int jb = tt * 100;
  const short8* Hn = hidK + (long)n * 8 * TV;

  // ---- phase 1: u-tile [192][100]; wave w does mf = 3w..3w+2
  f32x4 uacc[3][7];
  for (int a = 0; a < 3; ++a) for (int b = 0; b < 7; ++b)
    uacc[a][b] = (f32x4){0.f, 0.f, 0.f, 0.f};
  for (int c = 0; c < 2; ++c) {
    short8 bf[7];
#pragma unroll
    for (int jf = 0; jf < 7; ++jf)
      bf[jf] = Hn[(long)(c * 4 + q) * TV + jb + jf * 16 + lj];
#pragma unroll
    for (int ml = 0; ml < 3; ++ml) {
      short8 af = Wu[((w * 3 + ml) * 2 + c) * 64 + lane];
#pragma unroll
      for (int jf = 0; jf < 7; ++jf)
        uacc[ml][jf] = __builtin_amdgcn_mfma_f32_16x16x32_bf16(af, bf[jf], uacc[ml][jf], 0, 0, 0);
    }
  }
#pragma unroll
  for (int ml = 0; ml < 3; ++ml) {
    int row0 = (w * 3 + ml) * 16 + q * 4;
#pragma unroll
    for (int jf = 0; jf < 7; ++jf) {
      int col = jf * 16 + lj;
      if (col < 100) {
        int cc = (col / 25) * 32 + (col % 25);
#pragma unroll
        for (int r = 0; r < 4; ++r)
          uT[(row0 + r) * UST + cc] = f2b(uacc[ml][jf][r]);
      }
    }
  }
  __syncthreads();

  // ---- phase 2: mixing for t_local = w; B-frag = aligned ds_read_b128
  const int colt = w * 25;
  short8 attA[6];
#pragma unroll
  for (int i = 0; i < 3; ++i)
#pragma unroll
    for (int wf = 0; wf < 2; ++wf)
      attA[i * 2 + wf] = attP[((long)(n * 3 + i) * 2 + wf) * 64 + lane];

  f32x4 macc[2][4];
  for (int a = 0; a < 2; ++a) for (int b = 0; b < 4; ++b)
    macc[a][b] = (f32x4){0.f, 0.f, 0.f, 0.f};
#pragma unroll
  for (int i = 0; i < 3; ++i) {
#pragma unroll
    for (int of = 0; of < 4; ++of) {
      int row = i * 64 + of * 16 + lj;
      short8 bf = *(const short8*)&uT[row * UST + w * 32 + q * 8];
      macc[0][of] = __builtin_amdgcn_mfma_f32_16x16x32_bf16(attA[i * 2 + 0], bf, macc[0][of], 0, 0, 0);
      macc[1][of] = __builtin_amdgcn_mfma_f32_16x16x32_bf16(attA[i * 2 + 1], bf, macc[1][of], 0, 0, 0);
    }
  }
  __syncthreads();   // ALL uT reads done before sOut (aliased) writes
#pragma unroll
  for (int wf = 0; wf < 2; ++wf)
#pragma unroll
    for (int of = 0; of < 4; ++of)
#pragma unroll
      for (int r = 0; r < 4; ++r) {
        int wl = wf * 16 + q * 4 + r;
        if (wl < 25)
          sOut[(of * 16 + lj) * OST + colt + wl] = f2b(macc[wf][of][r]);
      }
  __syncthreads();

  // ---- epilogue: coalesced KJ8 in/out
  const short* HnS = (const short*)Hn;
  short* Gn = gcnK + (long)n * 64 * TV;
  for (int u2 = tid; u2 < 800; u2 += 256) {
    int col = u2 % 100, og = u2 / 100;
    long ubase = ((long)og * TV + jb + col) * 8;
    short8 h8 = *(const short8*)&HnS[ubase];
    short8 o8;
#pragma unroll
    for (int e = 0; e < 8; ++e) {
      int o = og * 8 + e;
      float acc = b2f(sOut[o * OST + col]);
      float vv = fmaxf(acc * A2[o] + B2[o] + b2f(h8[e]), 0.f);
      o8[e] = f2b(vv);
    }
    *(short8*)&Gn[ubase] = o8;
  }
}

// ===========================================================================
// TCN (j=128): weights staged ONCE per block in LDS (was: every wave from
// global = 4x redundant L2 traffic, ~940 MB). 9 shifted K=64 MFMA + tBN +
// residual relu -> msgK (KJ8).
// ===========================================================================
__global__ __launch_bounds__(256) void tcn_mfma(
    const short8* __restrict__ wTp, const short8* __restrict__ gcnK,
    const short* __restrict__ hidK, const float* __restrict__ tcn_b,
    const float* __restrict__ pbg, const float* __restrict__ pbb,
    const float* __restrict__ pbm, const float* __restrict__ pbv,
    short* __restrict__ msgK)
{
  __shared__ __align__(16) short8 sW[4608];   // 72 KB: all tcn weight frags
  __shared__ float A2[64], B2[64];
  const int tid = threadIdx.x;
  for (int idx = tid; idx < 4608; idx += 256) sW[idx] = wTp[idx];
  if (tid < 64) {
    float sc = pbg[tid] * rsqrtf(pbv[tid] + 1e-5f);
    A2[tid] = sc;
    B2[tid] = tcn_b[tid] * sc + (pbb[tid] - pbm[tid] * sc);
  }
  __syncthreads();
  const int lane = tid & 63, w = tid >> 6;
  const int q = lane >> 4, lj = lane & 15;
  const int j0 = blockIdx.x * 128;
  const int n = blockIdx.y;
  const short8* Bn = gcnK + (long)n * 8 * TV;
  const short8 zero8 = {0, 0, 0, 0, 0, 0, 0, 0};

  f32x4 acc[4][2];
  for (int a = 0; a < 4; ++a) for (int b = 0; b < 2; ++b)
    acc[a][b] = (f32x4){0.f, 0.f, 0.f, 0.f};

  for (int kk = 0; kk < 9; ++kk) {
    const int shift = (kk - 4) * 25;
    for (int c = 0; c < 2; ++c) {
      short8 bfv[2];
#pragma unroll
      for (int jf = 0; jf < 2; ++jf) {
        int col = j0 + (w * 2 + jf) * 16 + lj + shift;
        bool valid = ((unsigned)col < (unsigned)TV);
        short8 t = Bn[(long)(c * 4 + q) * TV + (valid ? col : 0)];
        bfv[jf] = valid ? t : zero8;
      }
#pragma unroll
      for (int mf = 0; mf < 4; ++mf) {
        short8 af = sW[((kk * 4 + mf) * 2 + c) * 64 + lane];
        acc[mf][0] = __builtin_amdgcn_mfma_f32_16x16x32_bf16(af, bfv[0], acc[mf][0], 0, 0, 0);
        acc[mf][1] = __builtin_amdgcn_mfma_f32_16x16x32_bf16(af, bfv[1], acc[mf][1], 0, 0, 0);
      }
    }
  }

  short* Mn = msgK + (long)n * 64 * TV;
  const short* Hn = hidK + (long)n * 64 * TV;
#pragma unroll
  for (int mf = 0; mf < 4; ++mf) {
    int k0 = mf * 16 + q * 4;
    int g = k0 >> 3, i0 = k0 & 7;
#pragma unroll
    for (int jf = 0; jf < 2; ++jf) {
      int j = j0 + (w * 2 + jf) * 16 + lj;
      long base = ((long)g * TV + j) * 8 + i0;
      short4v h4 = *(const short4v*)&Hn[base];
      short4v o4;
#pragma unroll
      for (int r = 0; r < 4; ++r) {
        float v = acc[mf][jf][r] * A2[k0 + r] + B2[k0 + r] + b2f(h4[r]);
        o4[r] = f2b(fmaxf(v, 0.f));
      }
      *(short4v*)&Mn[base] = o4;
    }
  }
}

// ===========================================================================
// GRU: F = WF@featK, H = WH@msgK (sW staged once/block), FAST gates,
// DIRECT global stores (no sOut LDS) -> LDS ~50 KB -> 3 blocks/CU.
// ===========================================================================
__global__ __launch_bounds__(256) void gru_mfma(
    const short8* __restrict__ WFp, const short8* __restrict__ WHp,
    const float* __restrict__ bF, const short8* __restrict__ featK,
    const short8* __restrict__ msgK, const short* __restrict__ hidK,
    float* __restrict__ outp)
{
  __shared__ __align__(16) short8 sW[3072];   // 48 KB
  __shared__ float sBias[192];
  const int tid = threadIdx.x;
  for (int idx = tid; idx < 1536; idx += 256) {
    sW[idx] = WFp[idx];
    sW[1536 + idx] = WHp[idx];
  }
  if (tid < 192) sBias[tid] = bF[tid];
  __syncthreads();

  const int lane = tid & 63, w = tid >> 6;
  const int q = lane >> 4, lj = lane & 15;
  const int j0 = blockIdx.x * 64;
  const int n = blockIdx.y;
  const int j = j0 + w * 16 + lj;
  const short8* Fn = featK + (long)n * 8 * TV;
  const short8* Mn = msgK + (long)n * 8 * TV;

  f32x4 accF[12], accH[12];
  for (int a = 0; a < 12; ++a) {
    accF[a] = (f32x4){0.f, 0.f, 0.f, 0.f};
    accH[a] = (f32x4){0.f, 0.f, 0.f, 0.f};
  }
  for (int c = 0; c < 2; ++c) {
    short8 bFf = Fn[(long)(c * 4 + q) * TV + j];
    short8 bHf = Mn[(long)(c * 4 + q) * TV + j];
#pragma unroll
    for (int mf = 0; mf < 12; ++mf) {
      short8 af = sW[(mf * 2 + c) * 64 + lane];
      accF[mf] = __builtin_amdgcn_mfma_f32_16x16x32_bf16(af, bFf, accF[mf], 0, 0, 0);
      short8 ah = sW[1536 + (mf * 2 + c) * 64 + lane];
      accH[mf] = __builtin_amdgcn_mfma_f32_16x16x32_bf16(ah, bHf, accH[mf], 0, 0, 0);
    }
  }

  const short* Hn = hidK + (long)n * 64 * TV;
  float* On = outp + (long)n * 64 * TV;
#pragma unroll
  for (int mf = 0; mf < 4; ++mf) {
    int k0 = mf * 16 + q * 4;
    int g = k0 >> 3, i0 = k0 & 7;
    short4v h4 = *(const short4v*)&Hn[((long)g * TV + j) * 8 + i0];
#pragma unroll
    for (int r = 0; r < 4; ++r) {
      int o = k0 + r;
      float rp = accF[mf][r] + sBias[o] + accH[mf][r];
      float zp = accF[mf + 4][r] + sBias[64 + o] + accH[mf + 4][r];
      float np = accF[mf + 8][r] + sBias[128 + o];
      float rv = fsig(rp);
      float zv = fsig(zp);
      float nn = ftanh(np + rv * accH[mf + 8][r]);
      float hv = b2f(h4[r]);
      On[(long)o * TV + j] = (1.f - zv) * nn + zv * hv;
    }
  }
}

// ===========================================================================
extern "C" void kernel_launch(void* const* d_in, const int* in_sizes, int n_in,
                              void* d_out, int out_size, void* d_ws, size_t ws_size,
                              hipStream_t stream)
{
  const float* feature = (const float*)d_in[0];
  const float* hidden  = (const float*)d_in[1];
  const float* Amat    = (const float*)d_in[2];
  const float* PAmat   = (const float*)d_in[3];
  const float* caw = (const float*)d_in[4];
  const float* cab = (const float*)d_in[5];
  const float* cbw = (const float*)d_in[6];
  const float* cbb = (const float*)d_in[7];
  const float* cdw = (const float*)d_in[8];
  const float* cdb = (const float*)d_in[9];
  const float* gbn_g = (const float*)d_in[10];
  const float* gbn_b = (const float*)d_in[11];
  const float* gbn_m = (const float*)d_in[12];
  const float* gbn_v = (const float*)d_in[13];
  const float* tcn_w = (const float*)d_in[14];
  const float* tcn_b = (const float*)d_in[15];
  const float* tbn_g = (const float*)d_in[16];
  const float* tbn_b = (const float*)d_in[17];
  const float* tbn_m = (const float*)d_in[18];
  const float* tbn_v = (const float*)d_in[19];
  const float* W_ir = (const float*)d_in[20];
  const float* W_ii = (const float*)d_in[21];
  const float* W_in = (const float*)d_in[22];
  const float* W_hr = (const float*)d_in[23];
  const float* W_hi = (const float*)d_in[24];
  const float* W_hh = (const float*)d_in[25];
  const float* b_ir = (const float*)d_in[26];
  const float* b_ii = (const float*)d_in[27];
  const float* b_in = (const float*)d_in[28];
  float* out = (float*)d_out;

  // n-chunk sizing (layout depends only on ws_size)
  int Nc = NTOT;
  while (Nc > 1) {
    size_t need = (size_t)352 * TV * 2 * Nc + (size_t)Nc * 30000 * 4 +
                  (size_t)Nc * 3072 * 2 + 79872 * 2 + 288 * 4 + 4096;
    if (need <= ws_size) break;
    Nc >>= 1;
  }

  char* p = (char*)d_ws;
  short* hidK = (short*)p;  p += (size_t)Nc * 64 * TV * 2;
  short* featK = (short*)p; p += (size_t)Nc * 64 * TV * 2;
  short* abK = (short*)p;   p += (size_t)Nc * 96 * TV * 2;
  short* gcnK = (short*)p;  p += (size_t)Nc * 64 * TV * 2;
  short* msgK = (short*)p;  p += (size_t)Nc * 64 * TV * 2;
  float* partial = (float*)p; p += (size_t)Nc * 30000 * 4;
  short* attP = (short*)p;    p += (size_t)Nc * 3072 * 2;
  p = (char*)(((size_t)p + 15) & ~(size_t)15);
  short* P = (short*)p;       p += 79872 * 2;
  float* Pb = (float*)p;

  pack_kernel<<<dim3(41), dim3(256), 0, stream>>>(
      tcn_w, caw, cbw, cdw, W_ir, W_ii, W_in, W_hr, W_hi, W_hh,
      cab, cbb, b_ir, b_ii, b_in, P, Pb);

  const long s64 = (long)64 * TV;
  for (int c0 = 0; c0 < NTOT; c0 += Nc) {
    const float* hidc = hidden + (long)c0 * s64;
    const float* featc = feature + (long)c0 * s64;
    float* outc = out + (long)c0 * s64;

    convert_kernel<<<dim3(25, 16, Nc), 256, 0, stream>>>(hidc, featc, hidK, featK);
    ab_gemm<<<dim3(50, Nc), 256, 0, stream>>>(
        (const short8*)P, (const short8*)hidK, abK, Pb);
    att_partial<<<dim3(16, 3, Nc), 256, 0, stream>>>(abK, partial);
    att_reduce<<<dim3(3, Nc), 256, 0, stream>>>(partial, Amat, PAmat, attP);
    gcn_fused<<<dim3(64, Nc), 256, 0, stream>>>(
        (const short8*)P + 768, (const short8*)attP, (const short8*)hidK,
        cdb, gbn_g, gbn_b, gbn_m, gbn_v, gcnK);
    tcn_mfma<<<dim3(50, Nc), 256, 0, stream>>>(
        (const short8*)P + 5376, (const short8*)gcnK, hidK, tcn_b,
        tbn_g, tbn_b, tbn_m, tbn_v, msgK);
    gru_mfma<<<dim3(100, Nc), 256, 0, stream>>>(
        (const short8*)P + 2304, (const short8*)P + 3840, Pb + 96,
        (const short8*)featK, (const short8*)msgK, hidK, outc);
  }
}

// Round 9
// 348.747 us; speedup vs baseline: 1.1175x; 1.0522x over previous
//
#include <hip/hip_runtime.h>
#include <math.h>

#define TV 6400
#define NTOT 32

typedef __attribute__((ext_vector_type(8))) short short8;
typedef __attribute__((ext_vector_type(4))) short short4v;
typedef __attribute__((ext_vector_type(4))) float f32x4;

__device__ __forceinline__ float b2f(short s) {
  unsigned u = ((unsigned)(unsigned short)s) << 16;
  return __uint_as_float(u);
}
__device__ __forceinline__ short f2b(float f) {
  unsigned u = __float_as_uint(f);
  u = (u + 0x7FFF + ((u >> 16) & 1)) >> 16;
  return (short)u;
}
__device__ __forceinline__ float fsig(float x) {
  return __builtin_amdgcn_rcpf(1.f + __expf(-x));
}
__device__ __forceinline__ float ftanh(float x) {
  float x2 = fminf(fmaxf(2.f * x, -80.f), 80.f);
  float t = __expf(x2);
  return (t - 1.f) * __builtin_amdgcn_rcpf(t + 1.f);
}

// ===========================================================================
// Pack weights to bf16 frag-major. Units: Wab[0,768) Wu[768,2304)
// WF[2304,3840) WH[3840,5376) wT[5376,9984). Biases fp32 in Pb.
// ===========================================================================
__global__ __launch_bounds__(256) void pack_kernel(
    const float* __restrict__ tcn_w, const float* __restrict__ caw,
    const float* __restrict__ cbw, const float* __restrict__ cdw,
    const float* __restrict__ W_ir, const float* __restrict__ W_ii,
    const float* __restrict__ W_in, const float* __restrict__ W_hr,
    const float* __restrict__ W_hi, const float* __restrict__ W_hh,
    const float* __restrict__ cab, const float* __restrict__ cbb,
    const float* __restrict__ b_ir, const float* __restrict__ b_ii,
    const float* __restrict__ b_in,
    short* __restrict__ P, float* __restrict__ Pb)
{
  int idx = blockIdx.x * 256 + threadIdx.x;
  if (idx < 9984) {
    int lane = idx & 63;
    int rest = idx >> 6;
    int c = rest & 1;
    rest >>= 1;
    int mloc = lane & 15, kb = c * 32 + (lane >> 4) * 8;
    short8 v;
    if (rest < 6) {            // Wab
      int m = rest * 16 + mloc;
      for (int i = 0; i < 8; ++i)
        v[i] = f2b(m < 48 ? caw[m * 64 + kb + i] : cbw[(m - 48) * 64 + kb + i]);
    } else if (rest < 18) {    // Wu = cdw
      int m = (rest - 6) * 16 + mloc;
      for (int i = 0; i < 8; ++i) v[i] = f2b(cdw[m * 64 + kb + i]);
    } else if (rest < 30) {    // WF
      int m = (rest - 18) * 16 + mloc;
      const float* W = (m < 64) ? W_ir : (m < 128 ? W_ii : W_in);
      int mr = m & 63;
      for (int i = 0; i < 8; ++i) v[i] = f2b(W[mr * 64 + kb + i]);
    } else if (rest < 42) {    // WH
      int m = (rest - 30) * 16 + mloc;
      const float* W = (m < 64) ? W_hr : (m < 128 ? W_hi : W_hh);
      int mr = m & 63;
      for (int i = 0; i < 8; ++i) v[i] = f2b(W[mr * 64 + kb + i]);
    } else {                   // wT
      int t = rest - 42;
      int kk = t >> 2, mf = t & 3;
      int o = mf * 16 + mloc;
      for (int i = 0; i < 8; ++i) v[i] = f2b(tcn_w[o * 576 + (kb + i) * 9 + kk]);
    }
    *(short8*)(P + (size_t)idx * 8) = v;
  } else if (idx < 9984 + 288) {
    int r = idx - 9984;
    if (r < 96) Pb[r] = (r < 48) ? cab[r] : cbb[r - 48];
    else {
      int q = r - 96;
      Pb[r] = (q < 64) ? b_ir[q] : (q < 128 ? b_ii[q - 64] : b_in[q - 128]);
    }
  }
}

// ===========================================================================
// fp32 hidden [64][TV] -> KJ8 bf16 [8][TV][8]
// ===========================================================================
__global__ __launch_bounds__(256) void convert_kernel(
    const float* __restrict__ hid, short* __restrict__ hidK)
{
  int j = blockIdx.x * 256 + threadIdx.x;
  int g = blockIdx.y;
  int n = blockIdx.z;
  const float* src = hid + ((long)n * 64 + (long)g * 8) * TV + j;
  short* dst = hidK + (((long)n * 8 + g) * TV + j) * 8;
  short8 o;
#pragma unroll
  for (int i = 0; i < 8; ++i) o[i] = f2b(src[(long)i * TV]);
  *(short8*)dst = o;
}

// ===========================================================================
// ab = (caw|cbw) @ hid, M=96 in ONE m-pass -> abK (KJ8)
// ===========================================================================
__global__ __launch_bounds__(256) void ab_gemm(
    const short8* __restrict__ Wp, const short8* __restrict__ Bk,
    short* __restrict__ Cout, const float* __restrict__ bias)
{
  const int tid = threadIdx.x;
  const int lane = tid & 63, w = tid >> 6;
  const int q = lane >> 4, lj = lane & 15;
  const int j0 = blockIdx.x * 128;
  const int n = blockIdx.y;
  const short8* Bn = Bk + (long)n * 8 * TV;
  short* Cn = Cout + (long)n * 96 * TV;

  f32x4 acc[6][2];
  for (int a = 0; a < 6; ++a) for (int b = 0; b < 2; ++b)
    acc[a][b] = (f32x4){0.f, 0.f, 0.f, 0.f};

  for (int c = 0; c < 2; ++c) {
    short8 bf0 = Bn[(long)(c * 4 + q) * TV + j0 + (w * 2 + 0) * 16 + lj];
    short8 bf1 = Bn[(long)(c * 4 + q) * TV + j0 + (w * 2 + 1) * 16 + lj];
#pragma unroll
    for (int mf = 0; mf < 6; ++mf) {
      short8 af = Wp[(mf * 2 + c) * 64 + lane];
      acc[mf][0] = __builtin_amdgcn_mfma_f32_16x16x32_bf16(af, bf0, acc[mf][0], 0, 0, 0);
      acc[mf][1] = __builtin_amdgcn_mfma_f32_16x16x32_bf16(af, bf1, acc[mf][1], 0, 0, 0);
    }
  }
#pragma unroll
  for (int mf = 0; mf < 6; ++mf) {
    int k0 = mf * 16 + q * 4;
    int g = k0 >> 3, i0 = k0 & 7;
    float bv[4];
#pragma unroll
    for (int r = 0; r < 4; ++r) bv[r] = bias[k0 + r];
#pragma unroll
    for (int jf = 0; jf < 2; ++jf) {
      int j = j0 + (w * 2 + jf) * 16 + lj;
      short4v o4;
#pragma unroll
      for (int r = 0; r < 4; ++r) o4[r] = f2b(acc[mf][jf][r] + bv[r]);
      *(short4v*)(Cn + ((long)g * TV + j) * 8 + i0) = o4;
    }
  }
}

// ===========================================================================
// Attention in ONE kernel via MFMA. Block = (i, n), 4 waves split K=4096.
// K-order k=(t,ic): quad q picks (t-offset=q>>1, ic-half=q&1) so an A/B frag
// is ONE short8 load from abK. logits -> LDS reduce -> softmax -> attP.
// R8 FIX: nb must be the UNIT-GROUP base (n*12*TV), since the final index
// is scaled by 8 — round 7 used the short base n*96*TV, so every n>0 read
// garbage (absmax 0.697 failure).
// ===========================================================================
__global__ __launch_bounds__(256) void att_mfma(
    const short* __restrict__ abK, const float* __restrict__ Amat,
    const float* __restrict__ PAmat, short* __restrict__ attP)
{
  const int i = blockIdx.x, n = blockIdx.y;
  __shared__ float sP[4096];   // 4 waves x 32x32 partials
  __shared__ float sL[640];
  const int tid = threadIdx.x;
  const int lane = tid & 63, w = tid >> 6;
  const int q = lane >> 4, lj = lane & 15;
  const long nb = (long)n * 12 * TV;   // unit-group base (x8 applied at index)
  const long ga = nb + (long)(2 * i + (q & 1)) * TV;
  const long gb = nb + (long)(6 + 2 * i + (q & 1)) * TV;
  const int tq = q >> 1;

  f32x4 acc[2][2];
  for (int a = 0; a < 2; ++a) for (int b = 0; b < 2; ++b)
    acc[a][b] = (f32x4){0.f, 0.f, 0.f, 0.f};

  for (int p = w * 32; p < w * 32 + 32; ++p) {
    long jb = (long)(2 * p + tq) * 25;
    short8 a0 = *(const short8*)&abK[(ga + jb + lj) * 8];
    short8 a1 = *(const short8*)&abK[(ga + jb + 16 + lj) * 8];
    short8 b0 = *(const short8*)&abK[(gb + jb + lj) * 8];
    short8 b1 = *(const short8*)&abK[(gb + jb + 16 + lj) * 8];
    acc[0][0] = __builtin_amdgcn_mfma_f32_16x16x32_bf16(a0, b0, acc[0][0], 0, 0, 0);
    acc[0][1] = __builtin_amdgcn_mfma_f32_16x16x32_bf16(a0, b1, acc[0][1], 0, 0, 0);
    acc[1][0] = __builtin_amdgcn_mfma_f32_16x16x32_bf16(a1, b0, acc[1][0], 0, 0, 0);
    acc[1][1] = __builtin_amdgcn_mfma_f32_16x16x32_bf16(a1, b1, acc[1][1], 0, 0, 0);
  }
  const float scale = 1.0f / 4096.0f;
#pragma unroll
  for (int mi = 0; mi < 2; ++mi)
#pragma unroll
    for (int wi = 0; wi < 2; ++wi)
#pragma unroll
      for (int r = 0; r < 4; ++r)
        sP[w * 1024 + (mi * 16 + q * 4 + r) * 32 + wi * 16 + lj] =
            acc[mi][wi][r] * scale;
  __syncthreads();

  for (int idx = tid; idx < 625; idx += 256) {
    int v = idx / 25, w2 = idx - v * 25;
    int o = v * 32 + w2;
    sL[idx] = sP[o] + sP[1024 + o] + sP[2048 + o] + sP[3072 + o];
  }
  __syncthreads();
  if (tid < 25) {
    const int w2 = tid;
    float mx = -1e30f;
#pragma unroll
    for (int v = 0; v < 25; ++v) mx = fmaxf(mx, sL[v * 25 + w2]);
    float e[25];
    float s = 0.f;
#pragma unroll
    for (int v = 0; v < 25; ++v) { e[v] = __expf(sL[v * 25 + w2] - mx); s += e[v]; }
    float inv = 1.f / s;
#pragma unroll
    for (int v = 0; v < 25; ++v)
      sL[v * 25 + w2] = e[v] * inv + Amat[i * 625 + v * 25 + w2] + PAmat[i * 625 + v * 25 + w2];
  }
  __syncthreads();
  if (tid < 128) {
    int wf = tid >> 6, lane2 = tid & 63;
    int q2 = lane2 >> 4, lj2 = lane2 & 15;
    int w2 = wf * 16 + lj2;
    short8 o = {0, 0, 0, 0, 0, 0, 0, 0};
    if (w2 < 25) {
#pragma unroll
      for (int e2 = 0; e2 < 8; ++e2) {
        int v = q2 * 8 + e2;
        if (v < 25) o[e2] = f2b(sL[v * 25 + w2]);
      }
    }
    *(short8*)(attP + (size_t)(((long)(n * 3 + i) * 2 + wf) * 64 + lane2) * 8) = o;
  }
}

// ===========================================================================
// FUSED GCN: u = cdw@hid (MFMA) -> LDS [o][t][v]; mixing MFMA; gBN+res+relu.
// sOut aliases uT; pad slots zeroed (NaN hazard, round 5).
// ===========================================================================
#define UST 136
#define OST 101
__global__ __launch_bounds__(256) void gcn_fused(
    const short8* __restrict__ Wu, const short8* __restrict__ attP,
    const short8* __restrict__ hidK, const float* __restrict__ cdb,
    const float* __restrict__ gg, const float* __restrict__ gb,
    const float* __restrict__ gm, const float* __restrict__ gv,
    short* __restrict__ gcnK)
{
  __shared__ __align__(16) short uT[192 * UST];
  __shared__ float A2[64], B2[64];
  short* sOut = uT;
  const int tid = threadIdx.x;
  if (tid < 64) {
    float sc = gg[tid] * rsqrtf(gv[tid] + 1e-5f);
    A2[tid] = sc;
    float bias = cdb[tid] + cdb[64 + tid] + cdb[128 + tid];
    B2[tid] = bias * sc + (gb[tid] - gm[tid] * sc);
  }
  for (int idx = tid; idx < 5376; idx += 256) {
    int row = idx / 28, rr = idx - row * 28;
    int g = rr / 7, s = 25 + (rr - g * 7);
    uT[row * UST + g * 32 + s] = 0;
  }
  const int lane = tid & 63, w = tid >> 6;
  const int q = lane >> 4, lj = lane & 15;
  const int tt = blockIdx.x, n = blockIdx.y;
  const int jb = tt * 100;
  const short8* Hn = hidK + (long)n * 8 * TV;

  f32x4 uacc[3][7];
  for (int a = 0; a < 3; ++a) for (int b = 0; b < 7; ++b)
    uacc[a][b] = (f32x4){0.f, 0.f, 0.f, 0.f};
  for (int c = 0; c < 2; ++c) {
    short8 bf[7];
#pragma unroll
    for (int jf = 0; jf < 7; ++jf)
      bf[jf] = Hn[(long)(c * 4 + q) * TV + jb + jf * 16 + lj];
#pragma unroll
    for (int ml = 0; ml < 3; ++ml) {
      short8 af = Wu[((w * 3 + ml) * 2 + c) * 64 + lane];
#pragma unroll
      for (int jf = 0; jf < 7; ++jf)
        uacc[ml][jf] = __builtin_amdgcn_mfma_f32_16x16x32_bf16(af, bf[jf], uacc[ml][jf], 0, 0, 0);
    }
  }
#pragma unroll
  for (int ml = 0; ml < 3; ++ml) {
    int row0 = (w * 3 + ml) * 16 + q * 4;
#pragma unroll
    for (int jf = 0; jf < 7; ++jf) {
      int col = jf * 16 + lj;
      if (col < 100) {
        int cc = (col / 25) * 32 + (col % 25);
#pragma unroll
        for (int r = 0; r < 4; ++r)
          uT[(row0 + r) * UST + cc] = f2b(uacc[ml][jf][r]);
      }
    }
  }
  __syncthreads();

  const int colt = w * 25;
  short8 attA[6];
#pragma unroll
  for (int i = 0; i < 3; ++i)
#pragma unroll
    for (int wf = 0; wf < 2; ++wf)
      attA[i * 2 + wf] = attP[((long)(n * 3 + i) * 2 + wf) * 64 + lane];

  f32x4 macc[2][4];
  for (int a = 0; a < 2; ++a) for (int b = 0; b < 4; ++b)
    macc[a][b] = (f32x4){0.f, 0.f, 0.f, 0.f};
#pragma unroll
  for (int i = 0; i < 3; ++i) {
#pragma unroll
    for (int of = 0; of < 4; ++of) {
      int row = i * 64 + of * 16 + lj;
      short8 bf = *(const short8*)&uT[row * UST + w * 32 + q * 8];
      macc[0][of] = __builtin_amdgcn_mfma_f32_16x16x32_bf16(attA[i * 2 + 0], bf, macc[0][of], 0, 0, 0);
      macc[1][of] = __builtin_amdgcn_mfma_f32_16x16x32_bf16(attA[i * 2 + 1], bf, macc[1][of], 0, 0, 0);
    }
  }
  __syncthreads();
#pragma unroll
  for (int wf = 0; wf < 2; ++wf)
#pragma unroll
    for (int of = 0; of < 4; ++of)
#pragma unroll
      for (int r = 0; r < 4; ++r) {
        int wl = wf * 16 + q * 4 + r;
        if (wl < 25)
          sOut[(of * 16 + lj) * OST + colt + wl] = f2b(macc[wf][of][r]);
      }
  __syncthreads();

  const short* HnS = (const short*)Hn;
  short* Gn = gcnK + (long)n * 64 * TV;
  for (int u2 = tid; u2 < 800; u2 += 256) {
    int col = u2 % 100, og = u2 / 100;
    long ubase = ((long)og * TV + jb + col) * 8;
    short8 h8 = *(const short8*)&HnS[ubase];
    short8 o8;
#pragma unroll
    for (int e = 0; e < 8; ++e) {
      int o = og * 8 + e;
      float acc = b2f(sOut[o * OST + col]);
      float vv = fmaxf(acc * A2[o] + B2[o] + b2f(h8[e]), 0.f);
      o8[e] = f2b(vv);
    }
    *(short8*)&Gn[ubase] = o8;
  }
}

// ===========================================================================
// TCN (j=128): weights staged once per block, then LOOP over 2 n's to
// amortize the 72 KB stage and double MFMA/block.
// ===========================================================================
__global__ __launch_bounds__(256) void tcn_mfma(
    const short8* __restrict__ wTp, const short8* __restrict__ gcnK,
    const short* __restrict__ hidK, const float* __restrict__ tcn_b,
    const float* __restrict__ pbg, const float* __restrict__ pbb,
    const float* __restrict__ pbm, const float* __restrict__ pbv,
    short* __restrict__ msgK, int Nchunk)
{
  __shared__ __align__(16) short8 sW[4608];   // 72 KB
  __shared__ float A2[64], B2[64];
  const int tid = threadIdx.x;
  for (int idx = tid; idx < 4608; idx += 256) sW[idx] = wTp[idx];
  if (tid < 64) {
    float sc = pbg[tid] * rsqrtf(pbv[tid] + 1e-5f);
    A2[tid] = sc;
    B2[tid] = tcn_b[tid] * sc + (pbb[tid] - pbm[tid] * sc);
  }
  __syncthreads();
  const int lane = tid & 63, w = tid >> 6;
  const int q = lane >> 4, lj = lane & 15;
  const int j0 = blockIdx.x * 128;
  const short8 zero8 = {0, 0, 0, 0, 0, 0, 0, 0};

  for (int ni = 0; ni < 2; ++ni) {
    const int n = blockIdx.y * 2 + ni;
    if (n >= Nchunk) break;
    const short8* Bn = gcnK + (long)n * 8 * TV;

    f32x4 acc[4][2];
    for (int a = 0; a < 4; ++a) for (int b = 0; b < 2; ++b)
      acc[a][b] = (f32x4){0.f, 0.f, 0.f, 0.f};

    for (int kk = 0; kk < 9; ++kk) {
      const int shift = (kk - 4) * 25;
      for (int c = 0; c < 2; ++c) {
        short8 bfv[2];
#pragma unroll
        for (int jf = 0; jf < 2; ++jf) {
          int col = j0 + (w * 2 + jf) * 16 + lj + shift;
          bool valid = ((unsigned)col < (unsigned)TV);
          short8 t = Bn[(long)(c * 4 + q) * TV + (valid ? col : 0)];
          bfv[jf] = valid ? t : zero8;
        }
#pragma unroll
        for (int mf = 0; mf < 4; ++mf) {
          short8 af = sW[((kk * 4 + mf) * 2 + c) * 64 + lane];
          acc[mf][0] = __builtin_amdgcn_mfma_f32_16x16x32_bf16(af, bfv[0], acc[mf][0], 0, 0, 0);
          acc[mf][1] = __builtin_amdgcn_mfma_f32_16x16x32_bf16(af, bfv[1], acc[mf][1], 0, 0, 0);
        }
      }
    }

    short* Mn = msgK + (long)n * 64 * TV;
    const short* Hn = hidK + (long)n * 64 * TV;
#pragma unroll
    for (int mf = 0; mf < 4; ++mf) {
      int k0 = mf * 16 + q * 4;
      int g = k0 >> 3, i0 = k0 & 7;
#pragma unroll
      for (int jf = 0; jf < 2; ++jf) {
        int j = j0 + (w * 2 + jf) * 16 + lj;
        long base = ((long)g * TV + j) * 8 + i0;
        short4v h4 = *(const short4v*)&Hn[base];
        short4v o4;
#pragma unroll
        for (int r = 0; r < 4; ++r) {
          float v = acc[mf][jf][r] * A2[k0 + r] + B2[k0 + r] + b2f(h4[r]);
          o4[r] = f2b(fmaxf(v, 0.f));
        }
        *(short4v*)&Mn[base] = o4;
      }
    }
  }
}

// ===========================================================================
// GRU: F = WF@feat (fp32, inline bf16 cvt), H = WH@msgK; fast gates; direct
// global stores.
// ===========================================================================
__global__ __launch_bounds__(256) void gru_mfma(
    const short8* __restrict__ WFp, const short8* __restrict__ WHp,
    const float* __restrict__ bF, const float* __restrict__ feat,
    const short8* __restrict__ msgK, const short* __restrict__ hidK,
    float* __restrict__ outp)
{
  __shared__ __align__(16) short8 sW[3072];   // 48 KB
  __shared__ float sBias[192];
  const int tid = threadIdx.x;
  for (int idx = tid; idx < 1536; idx += 256) {
    sW[idx] = WFp[idx];
    sW[1536 + idx] = WHp[idx];
  }
  if (tid < 192) sBias[tid] = bF[tid];
  __syncthreads();

  const int lane = tid & 63, w = tid >> 6;
  const int q = lane >> 4, lj = lane & 15;
  const int j0 = blockIdx.x * 64;
  const int n = blockIdx.y;
  const int j = j0 + w * 16 + lj;
  const float* Ffn = feat + (long)n * 64 * TV;
  const short8* Mn = msgK + (long)n * 8 * TV;

  f32x4 accF[12], accH[12];
  for (int a = 0; a < 12; ++a) {
    accF[a] = (f32x4){0.f, 0.f, 0.f, 0.f};
    accH[a] = (f32x4){0.f, 0.f, 0.f, 0.f};
  }
  for (int c = 0; c < 2; ++c) {
    short8 bFf;
#pragma unroll
    for (int e = 0; e < 8; ++e)
      bFf[e] = f2b(Ffn[(long)(c * 32 + q * 8 + e) * TV + j]);
    short8 bHf = Mn[(long)(c * 4 + q) * TV + j];
#pragma unroll
    for (int mf = 0; mf < 12; ++mf) {
      short8 af = sW[(mf * 2 + c) * 64 + lane];
      accF[mf] = __builtin_amdgcn_mfma_f32_16x16x32_bf16(af, bFf, accF[mf], 0, 0, 0);
      short8 ah = sW[1536 + (mf * 2 + c) * 64 + lane];
      accH[mf] = __builtin_amdgcn_mfma_f32_16x16x32_bf16(ah, bHf, accH[mf], 0, 0, 0);
    }
  }

  const short* Hn = hidK + (long)n * 64 * TV;
  float* On = outp + (long)n * 64 * TV;
#pragma unroll
  for (int mf = 0; mf < 4; ++mf) {
    int k0 = mf * 16 + q * 4;
    int g = k0 >> 3, i0 = k0 & 7;
    short4v h4 = *(const short4v*)&Hn[((long)g * TV + j) * 8 + i0];
#pragma unroll
    for (int r = 0; r < 4; ++r) {
      int o = k0 + r;
      float rp = accF[mf][r] + sBias[o] + accH[mf][r];
      float zp = accF[mf + 4][r] + sBias[64 + o] + accH[mf + 4][r];
      float np = accF[mf + 8][r] + sBias[128 + o];
      float rv = fsig(rp);
      float zv = fsig(zp);
      float nn = ftanh(np + rv * accH[mf + 8][r]);
      float hv = b2f(h4[r]);
      On[(long)o * TV + j] = (1.f - zv) * nn + zv * hv;
    }
  }
}

// ===========================================================================
extern "C" void kernel_launch(void* const* d_in, const int* in_sizes, int n_in,
                              void* d_out, int out_size, void* d_ws, size_t ws_size,
                              hipStream_t stream)
{
  const float* feature = (const float*)d_in[0];
  const float* hidden  = (const float*)d_in[1];
  const float* Amat    = (const float*)d_in[2];
  const float* PAmat   = (const float*)d_in[3];
  const float* caw = (const float*)d_in[4];
  const float* cab = (const float*)d_in[5];
  const float* cbw = (const float*)d_in[6];
  const float* cbb = (const float*)d_in[7];
  const float* cdw = (const float*)d_in[8];
  const float* cdb = (const float*)d_in[9];
  const float* gbn_g = (const float*)d_in[10];
  const float* gbn_b = (const float*)d_in[11];
  const float* gbn_m = (const float*)d_in[12];
  const float* gbn_v = (const float*)d_in[13];
  const float* tcn_w = (const float*)d_in[14];
  const float* tcn_b = (const float*)d_in[15];
  const float* tbn_g = (const float*)d_in[16];
  const float* tbn_b = (const float*)d_in[17];
  const float* tbn_m = (const float*)d_in[18];
  const float* tbn_v = (const float*)d_in[19];
  const float* W_ir = (const float*)d_in[20];
  const float* W_ii = (const float*)d_in[21];
  const float* W_in = (const float*)d_in[22];
  const float* W_hr = (const float*)d_in[23];
  const float* W_hi = (const float*)d_in[24];
  const float* W_hh = (const float*)d_in[25];
  const float* b_ir = (const float*)d_in[26];
  const float* b_ii = (const float*)d_in[27];
  const float* b_in = (const float*)d_in[28];
  float* out = (float*)d_out;

  // n-chunk sizing (layout depends only on ws_size)
  int Nc = NTOT;
  while (Nc > 1) {
    size_t need = (size_t)288 * TV * 2 * Nc + (size_t)Nc * 3072 * 2 +
                  79872 * 2 + 288 * 4 + 4096;
    if (need <= ws_size) break;
    Nc >>= 1;
  }

  char* p = (char*)d_ws;
  short* hidK = (short*)p;  p += (size_t)Nc * 64 * TV * 2;
  short* abK = (short*)p;   p += (size_t)Nc * 96 * TV * 2;
  short* gcnK = (short*)p;  p += (size_t)Nc * 64 * TV * 2;
  short* msgK = (short*)p;  p += (size_t)Nc * 64 * TV * 2;
  short* attP = (short*)p;  p += (size_t)Nc * 3072 * 2;
  p = (char*)(((size_t)p + 15) & ~(size_t)15);
  short* P = (short*)p;     p += 79872 * 2;
  float* Pb = (float*)p;

  pack_kernel<<<dim3(41), dim3(256), 0, stream>>>(
      tcn_w, caw, cbw, cdw, W_ir, W_ii, W_in, W_hr, W_hi, W_hh,
      cab, cbb, b_ir, b_ii, b_in, P, Pb);

  const long s64 = (long)64 * TV;
  for (int c0 = 0; c0 < NTOT; c0 += Nc) {
    const float* hidc = hidden + (long)c0 * s64;
    const float* featc = feature + (long)c0 * s64;
    float* outc = out + (long)c0 * s64;

    convert_kernel<<<dim3(25, 8, Nc), 256, 0, stream>>>(hidc, hidK);
    ab_gemm<<<dim3(50, Nc), 256, 0, stream>>>(
        (const short8*)P, (const short8*)hidK, abK, Pb);
    att_mfma<<<dim3(3, Nc), 256, 0, stream>>>(abK, Amat, PAmat, attP);
    gcn_fused<<<dim3(64, Nc), 256, 0, stream>>>(
        (const short8*)P + 768, (const short8*)attP, (const short8*)hidK,
        cdb, gbn_g, gbn_b, gbn_m, gbn_v, gcnK);
    tcn_mfma<<<dim3(50, (Nc + 1) / 2), 256, 0, stream>>>(
        (const short8*)P + 5376, (const short8*)gcnK, hidK, tcn_b,
        tbn_g, tbn_b, tbn_m, tbn_v, msgK, Nc);
    gru_mfma<<<dim3(100, Nc), 256, 0, stream>>>(
        (const short8*)P + 2304, (const short8*)P + 3840, Pb + 96,
        featc, (const short8*)msgK, hidK, outc);
  }
}